// Round 10
// baseline (150.180 us; speedup 1.0000x reference)
//
#include <hip/hip_runtime.h>
#include <stdint.h>

typedef int i32x4  __attribute__((ext_vector_type(4)));
typedef int i32x16 __attribute__((ext_vector_type(16)));

static constexpr int Mdim   = 16384;     // B*S = 8*2048
static constexpr int Kdim   = 2048;      // D_IN
static constexpr int Ndim   = 2048;      // D_OUT
static constexpr int WELEMS = Ndim * Kdim;   // 4194304

// Fragment-major pack layout (shared by packers and GEMM):
//   chunk(R, c) = 1024 B at base + (R*64 + c)*1024
//   byte l*16 + b of a chunk holds row R*32 + (l&31), k = c*32 + (l>>5)*16 + b
// so a lane's MFMA fragment is ONE contiguous global_load_dwordx4 at
// chunk_base + l*16  -> the GEMM needs no LDS at all (flatmm pattern).

// ---------------- K1: partial sums of |w| -----------------------------------
__global__ void k_abs_part(const float* __restrict__ w, float* __restrict__ part) {
  const float4* w4 = (const float4*)w;
  float s = 0.f;
  int idx = blockIdx.x * 256 + threadIdx.x;
  #pragma unroll 4
  for (int i = idx; i < WELEMS / 4; i += 256 * 256) {
    float4 v = w4[i];
    s += fabsf(v.x) + fabsf(v.y) + fabsf(v.z) + fabsf(v.w);
  }
  #pragma unroll
  for (int off = 32; off > 0; off >>= 1) s += __shfl_down(s, off);
  __shared__ float sm[4];
  if ((threadIdx.x & 63) == 0) sm[threadIdx.x >> 6] = s;
  __syncthreads();
  if (threadIdx.x == 0) part[blockIdx.x] = sm[0] + sm[1] + sm[2] + sm[3];
}

// ---------------- K2: finalize scale = mean(|w|) ----------------------------
__global__ void k_abs_final(const float* __restrict__ part, float* __restrict__ scal) {
  float s = part[threadIdx.x];           // exactly 256 partials, block = 256
  #pragma unroll
  for (int off = 32; off > 0; off >>= 1) s += __shfl_down(s, off);
  __shared__ float sm[4];
  if ((threadIdx.x & 63) == 0) sm[threadIdx.x >> 6] = s;
  __syncthreads();
  if (threadIdx.x == 0) scal[0] = (sm[0] + sm[1] + sm[2] + sm[3]) / (float)WELEMS;
}

__device__ __forceinline__ int quant4(float4 v, float sc) {
  int a = (int)rintf(v.x / sc); a = a < -128 ? -128 : (a > 127 ? 127 : a);
  int b = (int)rintf(v.y / sc); b = b < -128 ? -128 : (b > 127 ? 127 : b);
  int c = (int)rintf(v.z / sc); c = c < -128 ? -128 : (c > 127 ? 127 : c);
  int d = (int)rintf(v.w / sc); d = d < -128 ? -128 : (d > 127 ? 127 : d);
  return (a & 255) | ((b & 255) << 8) | ((c & 255) << 16) | ((d & 255) << 24);
}

__device__ __forceinline__ int tern4(float4 v, float s) {
  int a = (int)rintf(v.x / s); a = a < -1 ? -1 : (a > 1 ? 1 : a);
  int b = (int)rintf(v.y / s); b = b < -1 ? -1 : (b > 1 ? 1 : b);
  int c = (int)rintf(v.z / s); c = c < -1 ? -1 : (c > 1 ? 1 : c);
  int d = (int)rintf(v.w / s); d = d < -1 ? -1 : (d > 1 ? 1 : d);
  return (a & 255) | ((b & 255) << 8) | ((c & 255) << 16) | ((d & 255) << 24);
}

// LDS row stride for the transpose buffers: 2052 B (513 dwords, odd ->
// bank = (l*513 + k)%32 spreads 32 rows over all 32 banks; <=2-way = free).
static constexpr int LSTR = 2052;

// ---------------- K3: ternary weight quantize + fragment-major pack ---------
// grid 64 blocks x 512 thr (8 waves); block = 32 rows of w.
__global__ __launch_bounds__(512) void k_wquant(const float* __restrict__ w,
                                                char* __restrict__ wq,
                                                const float* __restrict__ scal) {
  __shared__ char sq[32 * LSTR];
  const float s  = scal[0] + 1e-8f;
  const int   Rg = blockIdx.x;
  const int   wv = threadIdx.x >> 6;     // 0..7
  const int   l  = threadIdx.x & 63;

  #pragma unroll
  for (int it = 0; it < 4; ++it) {
    const int rs = it * 8 + wv;          // row slot 0..31
    const float4* wr = (const float4*)(w + (size_t)(Rg * 32 + rs) * Kdim);
    #pragma unroll
    for (int c = 0; c < 8; ++c)
      *(int*)(&sq[rs * LSTR + (c * 64 + l) * 4]) = tern4(wr[c * 64 + l], s);
  }
  __syncthreads();
  char* dst = wq + (size_t)Rg * 65536;
  #pragma unroll
  for (int i = 0; i < 8; ++i) {
    const int c = i * 8 + wv;            // chunk 0..63
    int p[4];
    #pragma unroll
    for (int j = 0; j < 4; ++j)
      p[j] = *(const int*)(&sq[(l & 31) * LSTR + c * 32 + (l >> 5) * 16 + j * 4]);
    *(int4*)(dst + c * 1024 + l * 16) = make_int4(p[0], p[1], p[2], p[3]);
  }
}

// ---------------- K4: per-row absmax + int8 quantize + pack -----------------
// grid 512 blocks x 512 thr (8 waves); block = 32 rows of x. One row per
// wave-iter -> absmax is a pure shfl reduce; all global traffic coalesced.
__global__ __launch_bounds__(512) void k_xquant(const float* __restrict__ x,
                                                char* __restrict__ xq,
                                                float* __restrict__ xs) {
  __shared__ char sq[32 * LSTR];
  const int Rg = blockIdx.x;
  const int wv = threadIdx.x >> 6;       // 0..7
  const int l  = threadIdx.x & 63;

  #pragma unroll
  for (int it = 0; it < 4; ++it) {
    const int rs  = it * 8 + wv;
    const int row = Rg * 32 + rs;
    const float4* xr = (const float4*)(x + (size_t)row * Kdim);
    float4 v[8];
    float  m = 0.f;
    #pragma unroll
    for (int c = 0; c < 8; ++c) {
      v[c] = xr[c * 64 + l];
      m = fmaxf(m, fmaxf(fmaxf(fabsf(v[c].x), fabsf(v[c].y)),
                         fmaxf(fabsf(v[c].z), fabsf(v[c].w))));
    }
    #pragma unroll
    for (int off = 1; off < 64; off <<= 1) m = fmaxf(m, __shfl_xor(m, off));
    m = fmaxf(m, 1e-8f);
    const float sc = m / 127.0f;
    if (l == 0) xs[row] = sc;
    #pragma unroll
    for (int c = 0; c < 8; ++c)
      *(int*)(&sq[rs * LSTR + (c * 64 + l) * 4]) = quant4(v[c], sc);
  }
  __syncthreads();
  char* dst = xq + (size_t)Rg * 65536;
  #pragma unroll
  for (int i = 0; i < 8; ++i) {
    const int c = i * 8 + wv;
    int p[4];
    #pragma unroll
    for (int j = 0; j < 4; ++j)
      p[j] = *(const int*)(&sq[(l & 31) * LSTR + c * 32 + (l >> 5) * 16 + j * 4]);
    *(int4*)(dst + c * 1024 + l * 16) = make_int4(p[0], p[1], p[2], p[3]);
  }
}

// ---------------- K5: int8 MFMA GEMM, LDS-FREE (flatmm) ---------------------
// out = (scale*xs[m]) * (xq . wq^T) + bias
// 8 waves (2M x 4N), wave tile 128x64 = acc[4][2] of 32x32 mfma.
// Fragments load DIRECTLY global->VGPR from the fragment-major packed
// buffers (contiguous, coalesced). No LDS, no barriers: each wave is an
// independent double-buffered pipeline  LOAD(t+1); MFMA(t); LOAD(t+2);
// MFMA(t+1).  Compiler emits counted vmcnt per register dependency; waves
// on a SIMD desync so loads overlap MFMA across waves (no vmcnt(0) drain).
__global__ __launch_bounds__(512, 2) void k_gemm(
    const char* __restrict__ xq, const char* __restrict__ wq,
    const float* __restrict__ xs, const float* __restrict__ scal,
    const float* __restrict__ bias, float* __restrict__ out) {
  // XCD-aware bijective swizzle: 512 blocks, 512 % 8 == 0.
  const int hw  = blockIdx.x;
  const int lin = (hw & 7) * 64 + (hw >> 3);
  const int bm  = lin >> 3;               // 64 M-tiles
  const int bn  = lin & 7;                // 8 N-tiles

  const int tid = threadIdx.x;
  const int w   = tid >> 6;               // wave 0..7
  const int l   = tid & 63;
  const int wr  = w >> 2, wc = w & 3;     // 2 x 4 wave grid
  const int l16 = l * 16;

  // per-wave fragment bases (R-groups): A = bm*8 + wr*4 + mi, B = bn*8 + wc*2 + ni
  const char* gA = xq + (size_t)(bm * 8 + wr * 4) * 65536 + l16;
  const char* gB = wq + (size_t)(bn * 8 + wc * 2) * 65536 + l16;

#define LOADT(AB, BB, t_)                                                   \
  {                                                                         \
    _Pragma("unroll") for (int mi = 0; mi < 4; ++mi)                        \
      _Pragma("unroll") for (int ks = 0; ks < 2; ++ks)                      \
        AB[mi][ks] = *(const i32x4*)(gA + mi * 65536 + ((t_) * 2 + ks) * 1024); \
    _Pragma("unroll") for (int ni = 0; ni < 2; ++ni)                        \
      _Pragma("unroll") for (int ks = 0; ks < 2; ++ks)                      \
        BB[ni][ks] = *(const i32x4*)(gB + ni * 65536 + ((t_) * 2 + ks) * 1024); \
  }

#define MFMAT(AB, BB)                                                       \
  {                                                                         \
    __builtin_amdgcn_s_setprio(1);                                          \
    _Pragma("unroll") for (int ks = 0; ks < 2; ++ks)                        \
      _Pragma("unroll") for (int mi = 0; mi < 4; ++mi)                      \
        _Pragma("unroll") for (int ni = 0; ni < 2; ++ni)                    \
          acc[mi][ni] = __builtin_amdgcn_mfma_i32_32x32x32_i8(              \
              AB[mi][ks], BB[ni][ks], acc[mi][ni], 0, 0, 0);                \
    __builtin_amdgcn_s_setprio(0);                                          \
  }

  i32x16 acc[4][2] = {};
  i32x4  aA[4][2], bA[2][2], aB[4][2], bB[2][2];

  LOADT(aA, bA, 0);
  for (int t = 0; t < Kdim / 64; t += 2) {   // 32 K-tiles, 2 per iter
    LOADT(aB, bB, t + 1);
    MFMAT(aA, bA);
    if (t + 2 < Kdim / 64) LOADT(aA, bA, t + 2);
    MFMAT(aB, bB);
  }
#undef LOADT
#undef MFMAT

  // epilogue: C/D mapping col = lane&31, row = (r&3) + 8*(r>>2) + 4*(lane>>5)
  const float wsc = scal[0];
  const int   lhi = (l >> 5) * 4, lcol = l & 31;
  float bc[2];
  #pragma unroll
  for (int ni = 0; ni < 2; ++ni)
    bc[ni] = bias[bn * 256 + wc * 64 + ni * 32 + lcol];

  #pragma unroll
  for (int mi = 0; mi < 4; ++mi) {
    const int rb = bm * 256 + wr * 128 + mi * 32 + lhi;
    #pragma unroll
    for (int r = 0; r < 16; ++r) {
      const int   row = rb + (r & 3) + 8 * (r >> 2);
      const float sv  = wsc * xs[row];
      #pragma unroll
      for (int ni = 0; ni < 2; ++ni) {
        const int col = bn * 256 + wc * 64 + ni * 32 + lcol;
        out[(size_t)row * Ndim + col] = (float)acc[mi][ni][r] * sv + bc[ni];
      }
    }
  }
}

// ---------------- launch -----------------------------------------------------
extern "C" void kernel_launch(void* const* d_in, const int* in_sizes, int n_in,
                              void* d_out, int out_size, void* d_ws, size_t ws_size,
                              hipStream_t stream) {
  const float* x    = (const float*)d_in[0];
  const float* wgt  = (const float*)d_in[1];
  const float* bias = (const float*)d_in[2];
  float* out = (float*)d_out;

  float* ws_f = (float*)d_ws;
  float* scal = ws_f;               // 1 float
  float* part = ws_f + 64;          // 256 floats
  float* xs   = ws_f + 1024;        // 16384 floats
  char*  wq   = (char*)(ws_f + 20480);          // 4 MiB packed, 16B-aligned
  char*  xq   = wq + (size_t)WELEMS;            // 32 MiB packed, 16B-aligned

  hipLaunchKernelGGL(k_abs_part,  dim3(256),      dim3(256), 0, stream, wgt, part);
  hipLaunchKernelGGL(k_abs_final, dim3(1),        dim3(256), 0, stream, part, scal);
  hipLaunchKernelGGL(k_wquant,    dim3(64),       dim3(512), 0, stream, wgt, wq, scal);
  hipLaunchKernelGGL(k_xquant,    dim3(Mdim/32),  dim3(512), 0, stream, x, xq, xs);
  hipLaunchKernelGGL(k_gemm,      dim3((Mdim/256)*(Ndim/256)), dim3(512), 0, stream,
                     xq, wq, xs, scal, bias, out);
}

// Round 12
// 136.564 us; speedup vs baseline: 1.0997x; 1.0997x over previous
//
#include <hip/hip_runtime.h>
#include <stdint.h>

typedef int i32x4  __attribute__((ext_vector_type(4)));
typedef int i32x16 __attribute__((ext_vector_type(16)));

static constexpr int Mdim   = 16384;     // B*S = 8*2048
static constexpr int Kdim   = 2048;      // D_IN
static constexpr int Ndim   = 2048;      // D_OUT
static constexpr int WELEMS = Ndim * Kdim;   // 4194304

// Fragment-major pack layout (shared by packers and GEMM):
//   chunk(R, c) = 1024 B at base + (R*64 + c)*1024
//   byte l*16 + b of a chunk holds row R*32 + (l&31), k = c*32 + (l>>5)*16 + b

// ---------------- async global->LDS (16B per lane, lane-ordered dest) -------
__device__ __forceinline__ void gload_lds16(const void* g, void* l) {
  __builtin_amdgcn_global_load_lds(
      (const __attribute__((address_space(1))) void*)g,
      (__attribute__((address_space(3))) void*)l,
      16, 0, 0);
}

// ---------------- K1: partial sums of |w| -----------------------------------
__global__ void k_abs_part(const float* __restrict__ w, float* __restrict__ part) {
  const float4* w4 = (const float4*)w;
  float s = 0.f;
  int idx = blockIdx.x * 256 + threadIdx.x;
  #pragma unroll 4
  for (int i = idx; i < WELEMS / 4; i += 256 * 256) {
    float4 v = w4[i];
    s += fabsf(v.x) + fabsf(v.y) + fabsf(v.z) + fabsf(v.w);
  }
  #pragma unroll
  for (int off = 32; off > 0; off >>= 1) s += __shfl_down(s, off);
  __shared__ float sm[4];
  if ((threadIdx.x & 63) == 0) sm[threadIdx.x >> 6] = s;
  __syncthreads();
  if (threadIdx.x == 0) part[blockIdx.x] = sm[0] + sm[1] + sm[2] + sm[3];
}

// ---------------- K2: finalize scale = mean(|w|) ----------------------------
__global__ void k_abs_final(const float* __restrict__ part, float* __restrict__ scal) {
  float s = part[threadIdx.x];           // exactly 256 partials, block = 256
  #pragma unroll
  for (int off = 32; off > 0; off >>= 1) s += __shfl_down(s, off);
  __shared__ float sm[4];
  if ((threadIdx.x & 63) == 0) sm[threadIdx.x >> 6] = s;
  __syncthreads();
  if (threadIdx.x == 0) scal[0] = (sm[0] + sm[1] + sm[2] + sm[3]) / (float)WELEMS;
}

__device__ __forceinline__ int quant4(float4 v, float sc) {
  int a = (int)rintf(v.x / sc); a = a < -128 ? -128 : (a > 127 ? 127 : a);
  int b = (int)rintf(v.y / sc); b = b < -128 ? -128 : (b > 127 ? 127 : b);
  int c = (int)rintf(v.z / sc); c = c < -128 ? -128 : (c > 127 ? 127 : c);
  int d = (int)rintf(v.w / sc); d = d < -128 ? -128 : (d > 127 ? 127 : d);
  return (a & 255) | ((b & 255) << 8) | ((c & 255) << 16) | ((d & 255) << 24);
}

__device__ __forceinline__ int tern4(float4 v, float s) {
  int a = (int)rintf(v.x / s); a = a < -1 ? -1 : (a > 1 ? 1 : a);
  int b = (int)rintf(v.y / s); b = b < -1 ? -1 : (b > 1 ? 1 : b);
  int c = (int)rintf(v.z / s); c = c < -1 ? -1 : (c > 1 ? 1 : c);
  int d = (int)rintf(v.w / s); d = d < -1 ? -1 : (d > 1 ? 1 : d);
  return (a & 255) | ((b & 255) << 8) | ((c & 255) << 16) | ((d & 255) << 24);
}

// LDS row stride for the transpose buffers: 2052 B (513 dwords, odd ->
// bank = (l*513 + k)%32 spreads 32 rows over all 32 banks; <=2-way = free).
static constexpr int LSTR = 2052;

// ---------------- K3: ternary weight quantize + fragment-major pack ---------
__global__ __launch_bounds__(512) void k_wquant(const float* __restrict__ w,
                                                char* __restrict__ wq,
                                                const float* __restrict__ scal) {
  __shared__ char sq[32 * LSTR];
  const float s  = scal[0] + 1e-8f;
  const int   Rg = blockIdx.x;
  const int   wv = threadIdx.x >> 6;     // 0..7
  const int   l  = threadIdx.x & 63;

  #pragma unroll
  for (int it = 0; it < 4; ++it) {
    const int rs = it * 8 + wv;          // row slot 0..31
    const float4* wr = (const float4*)(w + (size_t)(Rg * 32 + rs) * Kdim);
    #pragma unroll
    for (int c = 0; c < 8; ++c)
      *(int*)(&sq[rs * LSTR + (c * 64 + l) * 4]) = tern4(wr[c * 64 + l], s);
  }
  __syncthreads();
  char* dst = wq + (size_t)Rg * 65536;
  #pragma unroll
  for (int i = 0; i < 8; ++i) {
    const int c = i * 8 + wv;            // chunk 0..63
    int p[4];
    #pragma unroll
    for (int j = 0; j < 4; ++j)
      p[j] = *(const int*)(&sq[(l & 31) * LSTR + c * 32 + (l >> 5) * 16 + j * 4]);
    *(int4*)(dst + c * 1024 + l * 16) = make_int4(p[0], p[1], p[2], p[3]);
  }
}

// ---------------- K4: per-row absmax + int8 quantize + pack -----------------
__global__ __launch_bounds__(512) void k_xquant(const float* __restrict__ x,
                                                char* __restrict__ xq,
                                                float* __restrict__ xs) {
  __shared__ char sq[32 * LSTR];
  const int Rg = blockIdx.x;
  const int wv = threadIdx.x >> 6;       // 0..7
  const int l  = threadIdx.x & 63;

  #pragma unroll
  for (int it = 0; it < 4; ++it) {
    const int rs  = it * 8 + wv;
    const int row = Rg * 32 + rs;
    const float4* xr = (const float4*)(x + (size_t)row * Kdim);
    float4 v[8];
    float  m = 0.f;
    #pragma unroll
    for (int c = 0; c < 8; ++c) {
      v[c] = xr[c * 64 + l];
      m = fmaxf(m, fmaxf(fmaxf(fabsf(v[c].x), fabsf(v[c].y)),
                         fmaxf(fabsf(v[c].z), fabsf(v[c].w))));
    }
    #pragma unroll
    for (int off = 1; off < 64; off <<= 1) m = fmaxf(m, __shfl_xor(m, off));
    m = fmaxf(m, 1e-8f);
    const float sc = m / 127.0f;
    if (l == 0) xs[row] = sc;
    #pragma unroll
    for (int c = 0; c < 8; ++c)
      *(int*)(&sq[rs * LSTR + (c * 64 + l) * 4]) = quant4(v[c], sc);
  }
  __syncthreads();
  char* dst = xq + (size_t)Rg * 65536;
  #pragma unroll
  for (int i = 0; i < 8; ++i) {
    const int c = i * 8 + wv;
    int p[4];
    #pragma unroll
    for (int j = 0; j < 4; ++j)
      p[j] = *(const int*)(&sq[(l & 31) * LSTR + c * 32 + (l >> 5) * 16 + j * 4]);
    *(int4*)(dst + c * 1024 + l * 16) = make_int4(p[0], p[1], p[2], p[3]);
  }
}

// ---------------- K5: int8 MFMA GEMM, 256x256, BK=64, ring-4, FINE PHASES ---
// out = (scale*xs[m]) * (xq . wq^T) + bias
// 8 waves (2M x 4N), wave tile 128x64 = acc[4][2] of 32x32 mfma.
// Per K-tile: TWO fine phases, each {ds_read frags for THIS phase; 2 staging
// gloads of tile t+3; [vmcnt(8) in phase B]; s_barrier; setprio(1); 8 MFMA;
// setprio(0); s_barrier}.  Tile-t gloads are confirmed landed one tile early
// (phase-B vmcnt of tile t-1), so phase reads never race the DMA. Staging into
// buf[(t+3)&3] = buf[(t-1)&3] is safe: t-1's reads completed before its last
// barrier (MFMA consumed them). vmcnt never drains to 0 until the tail.
__global__ __launch_bounds__(512, 2) void k_gemm(
    const char* __restrict__ xq, const char* __restrict__ wq,
    const float* __restrict__ xs, const float* __restrict__ scal,
    const float* __restrict__ bias, float* __restrict__ out) {
  __shared__ __attribute__((aligned(128))) char lds[4][32768];

  // XCD-aware bijective swizzle: 512 blocks, 512 % 8 == 0.
  const int hw  = blockIdx.x;
  const int lin = (hw & 7) * 64 + (hw >> 3);
  const int bm  = lin >> 3;               // 64 M-tiles
  const int bn  = lin & 7;                // 8 N-tiles

  const int tid = threadIdx.x;
  const int w   = tid >> 6;               // wave 0..7
  const int l   = tid & 63;
  const int wr  = w >> 2, wc = w & 3;     // 2 x 4 wave grid
  const int l16 = l * 16;

  const char* gA = xq + (size_t)(bm * 8 + w) * 65536 + l16;
  const char* gB = wq + (size_t)(bn * 8 + w) * 65536 + l16;
  const int   w2k = w * 2048;

#define STAGE_A(t_)                                                       \
  { char* sb = &lds[(t_) & 3][0]; const int kb_ = (t_) * 2048;            \
    gload_lds16(gA + kb_,        sb + w2k);                               \
    gload_lds16(gA + kb_ + 1024, sb + w2k + 1024); }
#define STAGE_B(t_)                                                       \
  { char* sb = &lds[(t_) & 3][0]; const int kb_ = (t_) * 2048;            \
    gload_lds16(gB + kb_,        sb + 16384 + w2k);                       \
    gload_lds16(gB + kb_ + 1024, sb + 16384 + w2k + 1024); }

  i32x16 acc[4][2] = {};
  i32x4  aF[2][2], bF[2][2];

  STAGE_A(0); STAGE_B(0); STAGE_A(1); STAGE_B(1); STAGE_A(2); STAGE_B(2);
  asm volatile("s_waitcnt vmcnt(8)" ::: "memory");   // tile 0 landed
  __builtin_amdgcn_s_barrier();
  asm volatile("" ::: "memory");

#define TILE(T_, DOSTG, VMTOK)                                              \
  {                                                                         \
    const char* base_ = &lds[(T_) & 3][0];                                  \
    /* ---- phase A: frags for mi=0,1 + B ---- */                           \
    _Pragma("unroll") for (int mi = 0; mi < 2; ++mi)                        \
      _Pragma("unroll") for (int ks = 0; ks < 2; ++ks)                      \
        aF[mi][ks] = *(const i32x4*)(base_ + ((wr*4+mi)*2+ks)*1024 + l16);  \
    _Pragma("unroll") for (int ni = 0; ni < 2; ++ni)                        \
      _Pragma("unroll") for (int ks = 0; ks < 2; ++ks)                      \
        bF[ni][ks] = *(const i32x4*)(base_ + 16384 + ((wc*2+ni)*2+ks)*1024 + l16); \
    if (DOSTG) STAGE_A((T_) + 3)                                            \
    __builtin_amdgcn_s_barrier();                                           \
    asm volatile("" ::: "memory");                                          \
    __builtin_amdgcn_s_setprio(1);                                          \
    _Pragma("unroll") for (int ks = 0; ks < 2; ++ks)                        \
      _Pragma("unroll") for (int mi = 0; mi < 2; ++mi)                      \
        _Pragma("unroll") for (int ni = 0; ni < 2; ++ni)                    \
          acc[mi][ni] = __builtin_amdgcn_mfma_i32_32x32x32_i8(              \
              aF[mi][ks], bF[ni][ks], acc[mi][ni], 0, 0, 0);                \
    __builtin_amdgcn_s_setprio(0);                                          \
    __builtin_amdgcn_s_barrier();                                           \
    asm volatile("" ::: "memory");                                          \
    /* ---- phase B: frags for mi=2,3 (bF held in regs) ---- */             \
    _Pragma("unroll") for (int mi = 0; mi < 2; ++mi)                        \
      _Pragma("unroll") for (int ks = 0; ks < 2; ++ks)                      \
        aF[mi][ks] = *(const i32x4*)(base_ + ((wr*4+mi+2)*2+ks)*1024 + l16);\
    if (DOSTG) STAGE_B((T_) + 3)                                            \
    VMTOK                                                                   \
    __builtin_amdgcn_s_barrier();                                           \
    asm volatile("" ::: "memory");                                          \
    __builtin_amdgcn_s_setprio(1);                                          \
    _Pragma("unroll") for (int ks = 0; ks < 2; ++ks)                        \
      _Pragma("unroll") for (int mi = 0; mi < 2; ++mi)                      \
        _Pragma("unroll") for (int ni = 0; ni < 2; ++ni)                    \
          acc[mi+2][ni] = __builtin_amdgcn_mfma_i32_32x32x32_i8(            \
              aF[mi][ks], bF[ni][ks], acc[mi+2][ni], 0, 0, 0);              \
    __builtin_amdgcn_s_setprio(0);                                          \
    __builtin_amdgcn_s_barrier();                                           \
    asm volatile("" ::: "memory");                                          \
  }

#define VM8  asm volatile("s_waitcnt vmcnt(8)" ::: "memory");
#define VM4  asm volatile("s_waitcnt vmcnt(4)" ::: "memory");
#define VM0  asm volatile("s_waitcnt vmcnt(0)" ::: "memory");
#define VMN

  for (int t = 0; t < 29; ++t)            // uniform: stage t+3, confirm t+1
    TILE(t, 1, VM8)
  TILE(29, 0, VM4)                        // confirm 30 (only 31 newer)
  TILE(30, 0, VM0)                        // confirm 31 (queue empties)
  TILE(31, 0, VMN)
#undef TILE
#undef STAGE_A
#undef STAGE_B
#undef VM8
#undef VM4
#undef VM0
#undef VMN

  // epilogue: C/D mapping col = lane&31, row = (r&3) + 8*(r>>2) + 4*(lane>>5)
  const float wsc = scal[0];
  const int   lhi = (l >> 5) * 4, lcol = l & 31;
  float bc[2];
  #pragma unroll
  for (int ni = 0; ni < 2; ++ni)
    bc[ni] = bias[bn * 256 + wc * 64 + ni * 32 + lcol];

  #pragma unroll
  for (int mi = 0; mi < 4; ++mi) {
    const int rb = bm * 256 + wr * 128 + mi * 32 + lhi;
    #pragma unroll
    for (int r = 0; r < 16; ++r) {
      const int   row = rb + (r & 3) + 8 * (r >> 2);
      const float sv  = wsc * xs[row];
      #pragma unroll
      for (int ni = 0; ni < 2; ++ni) {
        const int col = bn * 256 + wc * 64 + ni * 32 + lcol;
        out[(size_t)row * Ndim + col] = (float)acc[mi][ni][r] * sv + bc[ni];
      }
    }
  }
}

// ---------------- launch -----------------------------------------------------
extern "C" void kernel_launch(void* const* d_in, const int* in_sizes, int n_in,
                              void* d_out, int out_size, void* d_ws, size_t ws_size,
                              hipStream_t stream) {
  const float* x    = (const float*)d_in[0];
  const float* wgt  = (const float*)d_in[1];
  const float* bias = (const float*)d_in[2];
  float* out = (float*)d_out;

  float* ws_f = (float*)d_ws;
  float* scal = ws_f;               // 1 float
  float* part = ws_f + 64;          // 256 floats
  float* xs   = ws_f + 1024;        // 16384 floats
  char*  wq   = (char*)(ws_f + 20480);          // 4 MiB packed, 16B-aligned
  char*  xq   = wq + (size_t)WELEMS;            // 32 MiB packed, 16B-aligned

  hipLaunchKernelGGL(k_abs_part,  dim3(256),      dim3(256), 0, stream, wgt, part);
  hipLaunchKernelGGL(k_abs_final, dim3(1),        dim3(256), 0, stream, part, scal);
  hipLaunchKernelGGL(k_wquant,    dim3(64),       dim3(512), 0, stream, wgt, wq, scal);
  hipLaunchKernelGGL(k_xquant,    dim3(Mdim/32),  dim3(512), 0, stream, x, xq, xs);
  hipLaunchKernelGGL(k_gemm,      dim3((Mdim/256)*(Ndim/256)), dim3(512), 0, stream,
                     xq, wq, xs, scal, bias, out);
}

// Round 13
// 134.443 us; speedup vs baseline: 1.1171x; 1.0158x over previous
//
#include <hip/hip_runtime.h>
#include <stdint.h>

typedef int i32x4  __attribute__((ext_vector_type(4)));
typedef int i32x16 __attribute__((ext_vector_type(16)));

static constexpr int Mdim   = 16384;     // B*S = 8*2048
static constexpr int Kdim   = 2048;      // D_IN
static constexpr int Ndim   = 2048;      // D_OUT
static constexpr int WELEMS = Ndim * Kdim;   // 4194304

// Fragment-major pack layout (shared by packers and GEMM):
//   chunk(R, c) = 1024 B at base + (R*64 + c)*1024
//   byte l*16 + b of a chunk holds row R*32 + (l&31), k = c*32 + (l>>5)*16 + b

// ---------------- async global->LDS (16B per lane, lane-ordered dest) -------
__device__ __forceinline__ void gload_lds16(const void* g, void* l) {
  __builtin_amdgcn_global_load_lds(
      (const __attribute__((address_space(1))) void*)g,
      (__attribute__((address_space(3))) void*)l,
      16, 0, 0);
}

// ---------------- K1: partial sums of |w| -----------------------------------
__global__ void k_abs_part(const float* __restrict__ w, float* __restrict__ part) {
  const float4* w4 = (const float4*)w;
  float s = 0.f;
  int idx = blockIdx.x * 256 + threadIdx.x;
  #pragma unroll 4
  for (int i = idx; i < WELEMS / 4; i += 256 * 256) {
    float4 v = w4[i];
    s += fabsf(v.x) + fabsf(v.y) + fabsf(v.z) + fabsf(v.w);
  }
  #pragma unroll
  for (int off = 32; off > 0; off >>= 1) s += __shfl_down(s, off);
  __shared__ float sm[4];
  if ((threadIdx.x & 63) == 0) sm[threadIdx.x >> 6] = s;
  __syncthreads();
  if (threadIdx.x == 0) part[blockIdx.x] = sm[0] + sm[1] + sm[2] + sm[3];
}

// ---------------- K2: finalize scale = mean(|w|) ----------------------------
__global__ void k_abs_final(const float* __restrict__ part, float* __restrict__ scal) {
  float s = part[threadIdx.x];           // exactly 256 partials, block = 256
  #pragma unroll
  for (int off = 32; off > 0; off >>= 1) s += __shfl_down(s, off);
  __shared__ float sm[4];
  if ((threadIdx.x & 63) == 0) sm[threadIdx.x >> 6] = s;
  __syncthreads();
  if (threadIdx.x == 0) scal[0] = (sm[0] + sm[1] + sm[2] + sm[3]) / (float)WELEMS;
}

__device__ __forceinline__ int quant4(float4 v, float sc) {
  int a = (int)rintf(v.x / sc); a = a < -128 ? -128 : (a > 127 ? 127 : a);
  int b = (int)rintf(v.y / sc); b = b < -128 ? -128 : (b > 127 ? 127 : b);
  int c = (int)rintf(v.z / sc); c = c < -128 ? -128 : (c > 127 ? 127 : c);
  int d = (int)rintf(v.w / sc); d = d < -128 ? -128 : (d > 127 ? 127 : d);
  return (a & 255) | ((b & 255) << 8) | ((c & 255) << 16) | ((d & 255) << 24);
}

__device__ __forceinline__ int tern4(float4 v, float s) {
  int a = (int)rintf(v.x / s); a = a < -1 ? -1 : (a > 1 ? 1 : a);
  int b = (int)rintf(v.y / s); b = b < -1 ? -1 : (b > 1 ? 1 : b);
  int c = (int)rintf(v.z / s); c = c < -1 ? -1 : (c > 1 ? 1 : c);
  int d = (int)rintf(v.w / s); d = d < -1 ? -1 : (d > 1 ? 1 : d);
  return (a & 255) | ((b & 255) << 8) | ((c & 255) << 16) | ((d & 255) << 24);
}

// LDS row stride for the transpose buffers: 2052 B (513 dwords, odd ->
// bank = (l*513 + k)%32 spreads 32 rows over all 32 banks; <=2-way = free).
static constexpr int LSTR = 2052;

// ---------------- K3: ternary weight quantize + fragment-major pack ---------
__global__ __launch_bounds__(512) void k_wquant(const float* __restrict__ w,
                                                char* __restrict__ wq,
                                                const float* __restrict__ scal) {
  __shared__ char sq[32 * LSTR];
  const float s  = scal[0] + 1e-8f;
  const int   Rg = blockIdx.x;
  const int   wv = threadIdx.x >> 6;     // 0..7
  const int   l  = threadIdx.x & 63;

  #pragma unroll
  for (int it = 0; it < 4; ++it) {
    const int rs = it * 8 + wv;          // row slot 0..31
    const float4* wr = (const float4*)(w + (size_t)(Rg * 32 + rs) * Kdim);
    #pragma unroll
    for (int c = 0; c < 8; ++c)
      *(int*)(&sq[rs * LSTR + (c * 64 + l) * 4]) = tern4(wr[c * 64 + l], s);
  }
  __syncthreads();
  char* dst = wq + (size_t)Rg * 65536;
  #pragma unroll
  for (int i = 0; i < 8; ++i) {
    const int c = i * 8 + wv;            // chunk 0..63
    int p[4];
    #pragma unroll
    for (int j = 0; j < 4; ++j)
      p[j] = *(const int*)(&sq[(l & 31) * LSTR + c * 32 + (l >> 5) * 16 + j * 4]);
    *(int4*)(dst + c * 1024 + l * 16) = make_int4(p[0], p[1], p[2], p[3]);
  }
}

// ---------------- K4: per-row absmax + int8 quantize + pack -----------------
__global__ __launch_bounds__(512) void k_xquant(const float* __restrict__ x,
                                                char* __restrict__ xq,
                                                float* __restrict__ xs) {
  __shared__ char sq[32 * LSTR];
  const int Rg = blockIdx.x;
  const int wv = threadIdx.x >> 6;       // 0..7
  const int l  = threadIdx.x & 63;

  #pragma unroll
  for (int it = 0; it < 4; ++it) {
    const int rs  = it * 8 + wv;
    const int row = Rg * 32 + rs;
    const float4* xr = (const float4*)(x + (size_t)row * Kdim);
    float4 v[8];
    float  m = 0.f;
    #pragma unroll
    for (int c = 0; c < 8; ++c) {
      v[c] = xr[c * 64 + l];
      m = fmaxf(m, fmaxf(fmaxf(fabsf(v[c].x), fabsf(v[c].y)),
                         fmaxf(fabsf(v[c].z), fabsf(v[c].w))));
    }
    #pragma unroll
    for (int off = 1; off < 64; off <<= 1) m = fmaxf(m, __shfl_xor(m, off));
    m = fmaxf(m, 1e-8f);
    const float sc = m / 127.0f;
    if (l == 0) xs[row] = sc;
    #pragma unroll
    for (int c = 0; c < 8; ++c)
      *(int*)(&sq[rs * LSTR + (c * 64 + l) * 4]) = quant4(v[c], sc);
  }
  __syncthreads();
  char* dst = xq + (size_t)Rg * 65536;
  #pragma unroll
  for (int i = 0; i < 8; ++i) {
    const int c = i * 8 + wv;
    int p[4];
    #pragma unroll
    for (int j = 0; j < 4; ++j)
      p[j] = *(const int*)(&sq[(l & 31) * LSTR + c * 32 + (l >> 5) * 16 + j * 4]);
    *(int4*)(dst + c * 1024 + l * 16) = make_int4(p[0], p[1], p[2], p[3]);
  }
}

// ---------------- K5: int8 MFMA GEMM, 256x256, BK=64, RING-2 / 2 blocks/CU --
// out = (scale*xs[m]) * (xq . wq^T) + bias
// 8 waves (2M x 4N), wave tile 128x64 = acc[4][2] of 32x32 mfma.
// 64 KiB LDS -> TWO blocks co-resident per CU: block A's barrier/vmcnt stalls
// and its epilogue write-burst overlap block B's MFMA (cross-block pipe
// overlap, m114).  Per tile: {vmcnt(4); s_barrier; ds_read 12; MFMA 16;
// s_barrier; STAGE(t+2)}.  vmcnt(4) confirms tile t only -- tile t+1 (issued
// one full iteration earlier) stays in flight; no vmcnt(0) until the peeled
// last tile.  Bottom barrier protects buf[t&1] from the t+2 DMA overwrite.
__global__ __launch_bounds__(512, 2) void k_gemm(
    const char* __restrict__ xq, const char* __restrict__ wq,
    const float* __restrict__ xs, const float* __restrict__ scal,
    const float* __restrict__ bias, float* __restrict__ out) {
  __shared__ __attribute__((aligned(128))) char lds[2][32768];

  // XCD-aware bijective swizzle: 512 blocks, 512 % 8 == 0.
  const int hw  = blockIdx.x;
  const int lin = (hw & 7) * 64 + (hw >> 3);
  const int bm  = lin >> 3;               // 64 M-tiles
  const int bn  = lin & 7;                // 8 N-tiles

  const int tid = threadIdx.x;
  const int w   = tid >> 6;               // wave 0..7
  const int l   = tid & 63;
  const int wr  = w >> 2, wc = w & 3;     // 2 x 4 wave grid
  const int l16 = l * 16;

  const char* gA = xq + (size_t)(bm * 8 + w) * 65536 + l16;
  const char* gB = wq + (size_t)(bn * 8 + w) * 65536 + l16;
  const int   w2k = w * 2048;

#define STAGE(t_)                                                         \
  { char* sb = &lds[(t_) & 1][0]; const int kb_ = (t_) * 2048;            \
    gload_lds16(gA + kb_,        sb + w2k);                               \
    gload_lds16(gA + kb_ + 1024, sb + w2k + 1024);                        \
    gload_lds16(gB + kb_,        sb + 16384 + w2k);                       \
    gload_lds16(gB + kb_ + 1024, sb + 16384 + w2k + 1024); }

  i32x16 acc[4][2] = {};

  STAGE(0); STAGE(1);                     // 8 loads in flight

#define TILE(T_, VMTOK, DOSTG)                                              \
  {                                                                         \
    VMTOK                                                                   \
    __builtin_amdgcn_s_barrier();                                           \
    asm volatile("" ::: "memory");                                          \
    const char* base_ = &lds[(T_) & 1][0];                                  \
    i32x4 aF[4][2], bF[2][2];                                               \
    _Pragma("unroll") for (int mi = 0; mi < 4; ++mi)                        \
      _Pragma("unroll") for (int ks = 0; ks < 2; ++ks)                      \
        aF[mi][ks] = *(const i32x4*)(base_ + ((wr*4+mi)*2+ks)*1024 + l16);  \
    _Pragma("unroll") for (int ni = 0; ni < 2; ++ni)                        \
      _Pragma("unroll") for (int ks = 0; ks < 2; ++ks)                      \
        bF[ni][ks] = *(const i32x4*)(base_ + 16384 + ((wc*2+ni)*2+ks)*1024 + l16); \
    __builtin_amdgcn_s_setprio(1);                                          \
    _Pragma("unroll") for (int ks = 0; ks < 2; ++ks)                        \
      _Pragma("unroll") for (int mi = 0; mi < 4; ++mi)                      \
        _Pragma("unroll") for (int ni = 0; ni < 2; ++ni)                    \
          acc[mi][ni] = __builtin_amdgcn_mfma_i32_32x32x32_i8(              \
              aF[mi][ks], bF[ni][ks], acc[mi][ni], 0, 0, 0);                \
    __builtin_amdgcn_s_setprio(0);                                          \
    __builtin_amdgcn_s_barrier();                                           \
    asm volatile("" ::: "memory");                                          \
    if (DOSTG) STAGE((T_) + 2)                                              \
  }

#define VM4  asm volatile("s_waitcnt vmcnt(4)" ::: "memory");
#define VM0  asm volatile("s_waitcnt vmcnt(0)" ::: "memory");

  #pragma unroll 2
  for (int t = 0; t < 30; ++t)            // uniform: confirm t, stage t+2
    TILE(t, VM4, 1)
  TILE(30, VM4, 0)                        // tile 31 stays in flight
  TILE(31, VM0, 0)                        // queue empties
#undef TILE
#undef STAGE
#undef VM4
#undef VM0

  // epilogue: C/D mapping col = lane&31, row = (r&3) + 8*(r>>2) + 4*(lane>>5)
  const float wsc = scal[0];
  const int   lhi = (l >> 5) * 4, lcol = l & 31;
  float bc[2];
  #pragma unroll
  for (int ni = 0; ni < 2; ++ni)
    bc[ni] = bias[bn * 256 + wc * 64 + ni * 32 + lcol];

  #pragma unroll
  for (int mi = 0; mi < 4; ++mi) {
    const int rb = bm * 256 + wr * 128 + mi * 32 + lhi;
    #pragma unroll
    for (int r = 0; r < 16; ++r) {
      const int   row = rb + (r & 3) + 8 * (r >> 2);
      const float sv  = wsc * xs[row];
      #pragma unroll
      for (int ni = 0; ni < 2; ++ni) {
        const int col = bn * 256 + wc * 64 + ni * 32 + lcol;
        out[(size_t)row * Ndim + col] = (float)acc[mi][ni][r] * sv + bc[ni];
      }
    }
  }
}

// ---------------- launch -----------------------------------------------------
extern "C" void kernel_launch(void* const* d_in, const int* in_sizes, int n_in,
                              void* d_out, int out_size, void* d_ws, size_t ws_size,
                              hipStream_t stream) {
  const float* x    = (const float*)d_in[0];
  const float* wgt  = (const float*)d_in[1];
  const float* bias = (const float*)d_in[2];
  float* out = (float*)d_out;

  float* ws_f = (float*)d_ws;
  float* scal = ws_f;               // 1 float
  float* part = ws_f + 64;          // 256 floats
  float* xs   = ws_f + 1024;        // 16384 floats
  char*  wq   = (char*)(ws_f + 20480);          // 4 MiB packed, 16B-aligned
  char*  xq   = wq + (size_t)WELEMS;            // 32 MiB packed, 16B-aligned

  hipLaunchKernelGGL(k_abs_part,  dim3(256),      dim3(256), 0, stream, wgt, part);
  hipLaunchKernelGGL(k_abs_final, dim3(1),        dim3(256), 0, stream, part, scal);
  hipLaunchKernelGGL(k_wquant,    dim3(64),       dim3(512), 0, stream, wgt, wq, scal);
  hipLaunchKernelGGL(k_xquant,    dim3(Mdim/32),  dim3(512), 0, stream, x, xq, xs);
  hipLaunchKernelGGL(k_gemm,      dim3((Mdim/256)*(Ndim/256)), dim3(512), 0, stream,
                     xq, wq, xs, scal, bias, out);
}